// Round 10
// baseline (209.668 us; speedup 1.0000x reference)
//
#include <hip/hip_runtime.h>
#include <hip/hip_bf16.h>

#define B_DIM 64
#define T_DIM 512
#define H_DIM 1024

typedef __attribute__((ext_vector_type(4))) float f32x4;

// ws layout (bytes)
#define AQ8_OFF  0UL              // A fp8 ROW-MAJOR: 32768*1024 = 33554432
#define WQ8_OFF  33554432UL       // W fp8 ROW-MAJOR: 1024*1024  =  1048576
#define DEC_OFF  34603008UL       // 64*1024*4  =  262144
#define PART_OFF 34865152UL       // 32768*8*4  = 1048576
#define AT_OFF   35913728UL       // 32768*4    =  131072
// total 36044800 bytes

// ---- OCP e4m3fn encode (RNE, satfinite) / decode — self-consistent pair ----
__device__ __forceinline__ unsigned char f2e4m3(float x) {
  float a = fabsf(x);
  unsigned s = (__float_as_uint(x) >> 31) << 7;
  a = fminf(a, 448.0f);
  unsigned char r;
  if (a < 0.015625f) {                       // subnormal: m * 2^-9
    int mi = (int)rintf(a * 512.0f);         // 0..8
    r = (unsigned char)mi;                   // mi==8 -> 0x08 == 2^-6 (e=1,m=0)
  } else {
    int ep = (int)(__float_as_uint(a) >> 23) - 127;          // -6..8
    float scale = __uint_as_float((unsigned)(130 - ep) << 23); // 2^(3-ep)
    int mi = (int)rintf(a * scale);          // 8..16
    if (mi == 16) { mi = 8; ep++; }
    r = (unsigned char)(((ep + 7) << 3) | (mi - 8));
  }
  return (unsigned char)(r | s);
}
__device__ __forceinline__ float e4m3f(unsigned char v) {
  unsigned e = (v >> 3) & 15u, m = v & 7u;
  float mag = (e == 0) ? (float)m * 0.001953125f
                       : (float)(8 + m) * __uint_as_float((e + 117u) << 23);
  return (v & 0x80u) ? -mag : mag;
}

__device__ __forceinline__ void gload_lds16(const void* g, void* l) {
  __builtin_amdgcn_global_load_lds(
      (const __attribute__((address_space(1))) void*)g,
      (__attribute__((address_space(3))) void*)l, 16, 0, 0);
}

// K1: prep v4 — fully-linear streams, NO transpose (R1 shape).
// Thread handles 16 consecutive floats of one row: read 4xfloat4 (64B),
// write 64B concat copy, write 16B fp8 row-major.
__global__ __launch_bounds__(256) void prep_ws(
    const float* __restrict__ prev,
    const float* __restrict__ st,
    const float* __restrict__ Wp,
    float* __restrict__ out,
    unsigned char* __restrict__ Aq,
    unsigned char* __restrict__ Wq) {
  const long NA = 2097152;                // prev 16-float groups
  const long NW = 65536;                  // W 16-float groups
  long gid = (long)blockIdx.x * 256 + threadIdx.x;
  float4* out4 = (float4*)out;
  if (gid < NA) {
    long e = gid * 16;
    int m = (int)(e >> 10);               // b*512 + t
    int k0 = (int)(e & 1023);
    int b = m >> 9, t = m & 511;
    const float4* s4 = (const float4*)(prev + e);
    float4 f0 = s4[0], f1 = s4[1], f2 = s4[2], f3 = s4[3];
    float4* d4 = out4 + 16384 + (size_t)b * 131328 + (((size_t)t << 10) + k0 >> 2);
    d4[0] = f0; d4[1] = f1; d4[2] = f2; d4[3] = f3;
    unsigned char q[16];
    q[0]  = f2e4m3(f0.x * 4.f); q[1]  = f2e4m3(f0.y * 4.f);
    q[2]  = f2e4m3(f0.z * 4.f); q[3]  = f2e4m3(f0.w * 4.f);
    q[4]  = f2e4m3(f1.x * 4.f); q[5]  = f2e4m3(f1.y * 4.f);
    q[6]  = f2e4m3(f1.z * 4.f); q[7]  = f2e4m3(f1.w * 4.f);
    q[8]  = f2e4m3(f2.x * 4.f); q[9]  = f2e4m3(f2.y * 4.f);
    q[10] = f2e4m3(f2.z * 4.f); q[11] = f2e4m3(f2.w * 4.f);
    q[12] = f2e4m3(f3.x * 4.f); q[13] = f2e4m3(f3.y * 4.f);
    q[14] = f2e4m3(f3.z * 4.f); q[15] = f2e4m3(f3.w * 4.f);
    *(uint4*)(Aq + (size_t)m * 1024 + k0) = *(const uint4*)q;
  } else if (gid < NA + NW) {
    long e = (gid - NA) * 16;
    int n = (int)(e >> 10);
    int k0 = (int)(e & 1023);
    const float4* s4 = (const float4*)(Wp + e);
    float4 f0 = s4[0], f1 = s4[1], f2 = s4[2], f3 = s4[3];
    unsigned char q[16];
    q[0]  = f2e4m3(f0.x * 16.f); q[1]  = f2e4m3(f0.y * 16.f);
    q[2]  = f2e4m3(f0.z * 16.f); q[3]  = f2e4m3(f0.w * 16.f);
    q[4]  = f2e4m3(f1.x * 16.f); q[5]  = f2e4m3(f1.y * 16.f);
    q[6]  = f2e4m3(f1.z * 16.f); q[7]  = f2e4m3(f1.w * 16.f);
    q[8]  = f2e4m3(f2.x * 16.f); q[9]  = f2e4m3(f2.y * 16.f);
    q[10] = f2e4m3(f2.z * 16.f); q[11] = f2e4m3(f2.w * 16.f);
    q[12] = f2e4m3(f3.x * 16.f); q[13] = f2e4m3(f3.y * 16.f);
    q[14] = f2e4m3(f3.z * 16.f); q[15] = f2e4m3(f3.w * 16.f);
    *(uint4*)(Wq + (size_t)n * 1024 + k0) = *(const uint4*)q;
  } else {
    long j = gid - NA - NW;               // 16384 float4s of s_t
    int b = (int)(j >> 8), i = (int)(j & 255);
    out4[16384 + (size_t)b * 131328 + 131072 + i] = ((const float4*)st)[j];
  }
}

// K2: dec_fea[b][o] = sum_h s_t[b][h]*W_s[o][h] + b_s[o]
__global__ void dec_kernel(const float* __restrict__ st,
                           const float* __restrict__ Ws,
                           const float* __restrict__ bs,
                           float* __restrict__ dec) {
  int tid = threadIdx.x;
  int lane = tid & 63, w = tid >> 6;
  int o = blockIdx.x * 4 + w;
  const float4* wrow = (const float4*)(Ws + (size_t)o * H_DIM);
  float4 w0 = wrow[lane], w1 = wrow[64 + lane], w2 = wrow[128 + lane], w3 = wrow[192 + lane];
  const float4* st4 = (const float4*)st;
  float bias = bs[o];
  #pragma unroll 8
  for (int b = 0; b < B_DIM; b++) {
    const float4* s = st4 + (size_t)b * 256;
    float4 s0 = s[lane], s1 = s[64 + lane], s2 = s[128 + lane], s3 = s[192 + lane];
    float p = w0.x * s0.x + w0.y * s0.y + w0.z * s0.z + w0.w * s0.w
            + w1.x * s1.x + w1.y * s1.y + w1.z * s1.z + w1.w * s1.w
            + w2.x * s2.x + w2.y * s2.y + w2.z * s2.z + w2.w * s2.w
            + w3.x * s3.x + w3.y * s3.y + w3.z * s3.z + w3.w * s3.w;
    p += __shfl_xor(p, 1);  p += __shfl_xor(p, 2);
    p += __shfl_xor(p, 4);  p += __shfl_xor(p, 8);
    p += __shfl_xor(p, 16); p += __shfl_xor(p, 32);
    if (lane == 0) dec[(size_t)b * H_DIM + o] = p + bias;
  }
}

// K3: fp8 score GEMM from ROW-MAJOR fp8 A/W. 128x128 block, 2x2 waves of
// 64x64, BK=64 bytes. Staging uses R2's verified chunk-XOR swizzle
// (pre-swizzled global source + same XOR on read address).
// raw-barrier + counted-vmcnt(4). acc = 64*et.
__global__ __launch_bounds__(256, 3) void score_gemm(
    const unsigned char* __restrict__ Aq,
    const unsigned char* __restrict__ Wq,
    const float* __restrict__ dec,
    const float* __restrict__ v,
    float* __restrict__ part)
{
  __shared__ __align__(16) unsigned char ldsA[2][8192];
  __shared__ __align__(16) unsigned char ldsB[2][8192];

  int orig = blockIdx.x;                       // 2048 blocks
  int swz = (orig & 7) * 256 + (orig >> 3);    // bijective XCD swizzle
  int bm = swz >> 3, bn = swz & 7;

  int tid = threadIdx.x;
  int lane = tid & 63, w = tid >> 6;
  int wm = w >> 1, wn = w & 1;                 // 2x2 waves, 64x64 each
  size_t m0 = (size_t)bm * 128;
  int n0 = bn * 128;

  f32x4 acc[4][4];
  #pragma unroll
  for (int i = 0; i < 4; i++)
    #pragma unroll
    for (int j = 0; j < 4; j++) {
      f32x4 z; z.x = 0.f; z.y = 0.f; z.z = 0.f; z.w = 0.f;
      acc[i][j] = z;
    }

  // staging geometry: tile row = 64B = 4x16B chunks; 512 chunks; 2/thread.
  // chunk c: row=c>>2, sub=c&3; source sub' = sub ^ ((row>>1)&3); LDS linear.
  int c0 = tid, c1 = tid + 256;
  int r0 = c0 >> 2, sb0 = (c0 & 3) ^ ((r0 >> 1) & 3);
  int r1 = c1 >> 2, sb1 = (c1 & 3) ^ ((r1 >> 1) & 3);
  const unsigned char* gA0 = Aq + (m0 + r0) * 1024 + sb0 * 16;
  const unsigned char* gA1 = Aq + (m0 + r1) * 1024 + sb1 * 16;
  const unsigned char* gB0 = Wq + (size_t)(n0 + r0) * 1024 + sb0 * 16;
  const unsigned char* gB1 = Wq + (size_t)(n0 + r1) * 1024 + sb1 * 16;

  // read offsets: lane reads 8B of row ra at k-half j:
  // chunk cj = j*2 + (lr>>1), swz chunk = cj ^ ((ra>>1)&3), +8 if lr odd
  int lr = lane >> 4, lc = lane & 15;
  int off8 = (lr & 1) * 8;
  int offA[4][2], offB[4][2];
  #pragma unroll
  for (int f = 0; f < 4; f++) {
    int ra = wm * 64 + f * 16 + lc;
    int rb = wn * 64 + f * 16 + lc;
    #pragma unroll
    for (int j = 0; j < 2; j++) {
      int cj = j * 2 + (lr >> 1);
      offA[f][j] = ra * 64 + ((cj ^ ((ra >> 1) & 3)) << 4) + off8;
      offB[f][j] = rb * 64 + ((cj ^ ((rb >> 1) & 3)) << 4) + off8;
    }
  }

#define STAGE(buf, t) do { \
    size_t ko = (size_t)(t) * 64; \
    gload_lds16(gA0 + ko, &ldsA[(buf)][c0 * 16]); \
    gload_lds16(gA1 + ko, &ldsA[(buf)][c1 * 16]); \
    gload_lds16(gB0 + ko, &ldsB[(buf)][c0 * 16]); \
    gload_lds16(gB1 + ko, &ldsB[(buf)][c1 * 16]); \
  } while (0)

  STAGE(0, 0);

  #pragma unroll 2
  for (int t = 0; t < 16; t++) {
    int cur = t & 1, nxt = cur ^ 1;
    if (t < 15) {
      STAGE(nxt, t + 1);
      asm volatile("s_waitcnt vmcnt(4)" ::: "memory");
    } else {
      asm volatile("s_waitcnt vmcnt(0)" ::: "memory");
    }
    __builtin_amdgcn_s_barrier();
    asm volatile("" ::: "memory");

    const unsigned char* Ac = &ldsA[cur][0];
    const unsigned char* Bc = &ldsB[cur][0];
    long av[4][2], bv[4][2];
    #pragma unroll
    for (int mf = 0; mf < 4; mf++)
      #pragma unroll
      for (int kk = 0; kk < 2; kk++)
        av[mf][kk] = *(const long*)(Ac + offA[mf][kk]);
    #pragma unroll
    for (int nf = 0; nf < 4; nf++)
      #pragma unroll
      for (int kk = 0; kk < 2; kk++)
        bv[nf][kk] = *(const long*)(Bc + offB[nf][kk]);

    __builtin_amdgcn_s_setprio(1);
    #pragma unroll
    for (int kk = 0; kk < 2; kk++)
      #pragma unroll
      for (int mf = 0; mf < 4; mf++)
        #pragma unroll
        for (int nf = 0; nf < 4; nf++)
          acc[mf][nf] = __builtin_amdgcn_mfma_f32_16x16x32_fp8_fp8(
              av[mf][kk], bv[nf][kk], acc[mf][nf], 0, 0, 0);
    __builtin_amdgcn_s_setprio(0);
    asm volatile("" ::: "memory");
    __builtin_amdgcn_s_barrier();
  }
#undef STAGE

  // epilogue: x = acc/64 + dec; tanh; dot v; 16-col shfl reduce; wn-pair via LDS
  int b = (int)(m0 >> 9);
  float dv[4], vv[4];
  #pragma unroll
  for (int nf = 0; nf < 4; nf++) {
    int col = n0 + wn * 64 + nf * 16 + lc;
    dv[nf] = dec[(size_t)b * H_DIM + col];
    vv[nf] = v[col];
  }
  float* epi = (float*)&ldsA[0][0];  // [128 rows][2 wn] floats = 1KB
  #pragma unroll
  for (int mf = 0; mf < 4; mf++) {
    #pragma unroll
    for (int r = 0; r < 4; r++) {
      float s = 0.f;
      #pragma unroll
      for (int nf = 0; nf < 4; nf++) {
        float x = acc[mf][nf][r] * 0.015625f + dv[nf];
        x = fminf(fmaxf(x, -15.f), 15.f);
        float e = __expf(2.f * x);
        s += vv[nf] * (e - 1.f) * __builtin_amdgcn_rcpf(e + 1.f);
      }
      s += __shfl_xor(s, 1); s += __shfl_xor(s, 2);
      s += __shfl_xor(s, 4); s += __shfl_xor(s, 8);
      if (lc == 0) epi[(wm * 64 + mf * 16 + lr * 4 + r) * 2 + wn] = s;
    }
  }
  __syncthreads();
  if (tid < 128) {
    part[(m0 + tid) * 8 + bn] = epi[tid * 2] + epi[tid * 2 + 1];
  }
}

// K4: softmax over T per batch row (8 partials per row)
__global__ void softmax_kernel(const float* __restrict__ part, float* __restrict__ at) {
  int b = blockIdx.x, tid = threadIdx.x;
  __shared__ float sc[512];
  __shared__ float red[8];
  #pragma unroll
  for (int rep = 0; rep < 2; rep++) {
    int t = rep * 256 + tid;
    const float* p = part + ((size_t)b * 512 + t) * 8;
    sc[t] = p[0] + p[1] + p[2] + p[3] + p[4] + p[5] + p[6] + p[7];
  }
  __syncthreads();
  float m = fmaxf(sc[tid], sc[tid + 256]);
  for (int d = 1; d < 64; d <<= 1) m = fmaxf(m, __shfl_xor(m, d));
  if ((tid & 63) == 0) red[tid >> 6] = m;
  __syncthreads();
  m = fmaxf(fmaxf(red[0], red[1]), fmaxf(red[2], red[3]));
  float e0 = __expf(sc[tid] - m), e1 = __expf(sc[tid + 256] - m);
  float s = e0 + e1;
  for (int d = 1; d < 64; d <<= 1) s += __shfl_xor(s, d);
  if ((tid & 63) == 0) red[4 + (tid >> 6)] = s;
  __syncthreads();
  s = red[4] + red[5] + red[6] + red[7];
  float inv = 1.f / s;
  at[(size_t)b * 512 + tid] = e0 * inv;
  at[(size_t)b * 512 + tid + 256] = e1 * inv;
}

// K5: ct_d[b][h] = sum_t at[b][t]*prev[b][t][h] from ROW-MAJOR fp8
// (values 4x -> scale 0.25). 512 blocks = 64 b x 8 t-chunks; atomics.
__global__ void ctd_kernel(const unsigned char* __restrict__ A8,
                           const float* __restrict__ at, float* __restrict__ out) {
  int blk = blockIdx.x;
  int b = blk >> 3, tc = blk & 7;
  int tid = threadIdx.x;
  int h = tid * 4;
  float a0 = 0.f, a1 = 0.f, a2 = 0.f, a3 = 0.f;
  const unsigned char* base = A8 + ((size_t)b * T_DIM + (size_t)tc * 64) * H_DIM + h;
  const float* atb = at + (size_t)b * T_DIM + tc * 64;
  #pragma unroll 4
  for (int i = 0; i < 64; i++) {
    float a = atb[i];
    uchar4 u = *(const uchar4*)(base + (size_t)i * H_DIM);
    a0 += a * e4m3f(u.x); a1 += a * e4m3f(u.y);
    a2 += a * e4m3f(u.z); a3 += a * e4m3f(u.w);
  }
  atomicAdd(&out[(size_t)b * H_DIM + h + 0], a0 * 0.25f);
  atomicAdd(&out[(size_t)b * H_DIM + h + 1], a1 * 0.25f);
  atomicAdd(&out[(size_t)b * H_DIM + h + 2], a2 * 0.25f);
  atomicAdd(&out[(size_t)b * H_DIM + h + 3], a3 * 0.25f);
}

extern "C" void kernel_launch(void* const* d_in, const int* in_sizes, int n_in,
                              void* d_out, int out_size, void* d_ws, size_t ws_size,
                              hipStream_t stream) {
  (void)in_sizes; (void)n_in; (void)out_size; (void)ws_size;
  const float* s_t    = (const float*)d_in[0];
  const float* prev_s = (const float*)d_in[1];
  const float* W_prev = (const float*)d_in[2];
  const float* W_s    = (const float*)d_in[3];
  const float* b_s    = (const float*)d_in[4];
  const float* v      = (const float*)d_in[5];
  float* out = (float*)d_out;
  char* ws = (char*)d_ws;

  unsigned char* Aq = (unsigned char*)(ws + AQ8_OFF);
  unsigned char* Wq = (unsigned char*)(ws + WQ8_OFF);
  float* dec  = (float*)(ws + DEC_OFF);
  float* part = (float*)(ws + PART_OFF);
  float* at   = (float*)(ws + AT_OFF);

  // zero ct_d region (atomics accumulate into it)
  hipMemsetAsync(d_out, 0, (size_t)B_DIM * H_DIM * sizeof(float), stream);

  prep_ws<<<8512, 256, 0, stream>>>(prev_s, s_t, W_prev, out, Aq, Wq);
  dec_kernel<<<256, 256, 0, stream>>>(s_t, W_s, b_s, dec);
  score_gemm<<<2048, 256, 0, stream>>>(Aq, Wq, dec, v, part);
  softmax_kernel<<<64, 256, 0, stream>>>(part, at);
  ctd_kernel<<<512, 256, 0, stream>>>(Aq, at, out);
}